// Round 10
// baseline (303.623 us; speedup 1.0000x reference)
//
#include <hip/hip_runtime.h>
#include <hip/hip_bf16.h>
#include <stdint.h>

// MMoE: E=16 experts, T=4 tasks, H=512, I=1024, B=8192.
// out[t,b] = sum_e g[b,t,e] * (sum_h relu(x@We^T+be)[b,e,h] * Wf[t,h]) + bf[t]
// R9 finding: barrier-pair cost measured at ~1.05 µs each (32->16 pairs saved
// 16.8 µs). R10: ping-pong double-buffer at BK=64 -> ONE barrier per K-iter
// (17 events vs 32) + prefetch latency hidden under the 32-MFMA compute
// section. Staging layout per 128x32 sub-buffer byte-identical to R9
// (verified 0-conflict swizzle). LDS 64 KB -> 2 blocks/CU (occupancy risk
// hedged: currently ~2.5). Epilogue + logits + cvt3 + reduce unchanged.

#define E_ 16
#define T_ 4
#define H_ 512
#define I_ 1024
#define B_ 8192
#define N_ (E_ * H_) /* 8192 */
#define K_ I_        /* 1024 */

typedef __bf16 bf16x8 __attribute__((ext_vector_type(8)));
typedef float f32x4 __attribute__((ext_vector_type(4)));

__device__ __forceinline__ unsigned short f2bf_rne(float f) {
  unsigned int b = __float_as_uint(f);
  b += 0x7fffu + ((b >> 16) & 1u);
  return (unsigned short)(b >> 16);
}

#define N4X (B_ * K_ / 4) /* 2097152 */
#define N4W (N_ * K_ / 4) /* 2097152 */
#define N4G (64 * K_ / 4) /* 16384 */

// merged fp32 -> bf16 (RNE) for x | We | Wg, float4 in / ushort4 out
__global__ __launch_bounds__(256) void cvt3_kernel(const float* __restrict__ x,
                                                   const float* __restrict__ We,
                                                   const float* __restrict__ Wg,
                                                   unsigned short* __restrict__ xb,
                                                   unsigned short* __restrict__ wb,
                                                   unsigned short* __restrict__ wgb) {
  int i = blockIdx.x * 256 + threadIdx.x;
  const float* src;
  unsigned short* dst;
  int j;
  if (i < N4X) {
    src = x; dst = xb; j = i;
  } else if (i < N4X + N4W) {
    src = We; dst = wb; j = i - N4X;
  } else if (i < N4X + N4W + N4G) {
    src = Wg; dst = wgb; j = i - (N4X + N4W);
  } else {
    return;
  }
  float4 v = reinterpret_cast<const float4*>(src)[j];
  ushort4 o;
  o.x = f2bf_rne(v.x);
  o.y = f2bf_rne(v.y);
  o.z = f2bf_rne(v.z);
  o.w = f2bf_rne(v.w);
  reinterpret_cast<ushort4*>(dst)[j] = o;
}

__device__ __forceinline__ void gld_lds16(const void* gp, void* lp) {
  __builtin_amdgcn_global_load_lds((const __attribute__((address_space(1))) void*)gp,
                                   (__attribute__((address_space(3))) void*)lp, 16, 0, 0);
}

// logits L[b][te] = x[b,:]@Wg[te,:] + bg[te] via bf16 MFMA (Wg [T][E][I] is
// already B^T [64][1024]), then softmax over e (= the 16 m16-lanes) in
// registers -> g[b][64]. Tile: M=128, N=64, BK=32; 4 waves x 32 rows each.
__global__ __launch_bounds__(256) void logits_softmax_kernel(
    const unsigned short* __restrict__ A,    // x bf16 [B_][K_]
    const unsigned short* __restrict__ Bm,   // Wg bf16 [64][K_]
    const float* __restrict__ bg,            // [64]
    float* __restrict__ g)                   // [B_][64]
{
  __shared__ struct {
    unsigned short A[128 * 32];  // 8 KB
    unsigned short B[64 * 32];   // 4 KB
  } st;

  const int tid = threadIdx.x;
  const int w = tid >> 6, l = tid & 63;
  const int m16 = l & 15, q = l >> 4;
  const size_t m0 = (size_t)blockIdx.x * 128;

  // A staging: rows w*32..w*32+31, 2 chunks/thread
  const int r0s = (w * 2 + 0) * 16 + (l >> 2);
  const int r1s = (w * 2 + 1) * 16 + (l >> 2);
  const int slot = l & 3;
  const int c0 = slot ^ ((r0s >> 1) & 3);
  const int c1 = slot ^ ((r1s >> 1) & 3);
  const size_t offA0 = (m0 + r0s) * K_ + c0 * 8;
  const size_t offA1 = (m0 + r1s) * K_ + c1 * 8;
  const int l0 = (w * 2 + 0) * 512;
  const int l1 = (w * 2 + 1) * 512;
  // B staging: 64 rows, 1 chunk/thread; wave w covers rows w*16..w*16+15
  const int rBs = w * 16 + (l >> 2);
  const int cB = slot ^ ((rBs >> 1) & 3);
  const size_t offB = (size_t)rBs * K_ + cB * 8;
  const int lB = w * 512;

  const int arow = w * 32 + m16;
  const int sA = q ^ ((arow >> 1) & 3);
  const int sB = q ^ ((m16 >> 1) & 3);

  f32x4 acc[2][4] = {};

  for (int k0 = 0; k0 < K_; k0 += 32) {
    __syncthreads();
    gld_lds16(A + offA0 + k0, st.A + l0);
    gld_lds16(A + offA1 + k0, st.A + l1);
    gld_lds16(Bm + offB + k0, st.B + lB);
    __syncthreads();
    bf16x8 af[2], bfr[4];
#pragma unroll
    for (int i = 0; i < 2; ++i)
      af[i] = *reinterpret_cast<const bf16x8*>(st.A + (arow + i * 16) * 32 + sA * 8);
#pragma unroll
    for (int j = 0; j < 4; ++j)
      bfr[j] = *reinterpret_cast<const bf16x8*>(st.B + (j * 16 + m16) * 32 + sB * 8);
#pragma unroll
    for (int i = 0; i < 2; ++i)
#pragma unroll
      for (int j = 0; j < 4; ++j)
        acc[i][j] = __builtin_amdgcn_mfma_f32_16x16x32_bf16(af[i], bfr[j], acc[i][j], 0, 0, 0);
  }

  // acc[i][j][r] = L[row = w*32+16i+4q+r][te = j*16+m16]; t = j, e = m16.
  float bgv[4];
#pragma unroll
  for (int j = 0; j < 4; ++j) bgv[j] = bg[j * 16 + m16];

#pragma unroll
  for (int i = 0; i < 2; ++i) {
    float lg[4][4];  // [r][j]
#pragma unroll
    for (int j = 0; j < 4; ++j)
#pragma unroll
      for (int r = 0; r < 4; ++r) lg[r][j] = acc[i][j][r] + bgv[j];
#pragma unroll
    for (int r = 0; r < 4; ++r) {
#pragma unroll
      for (int j = 0; j < 4; ++j) {
        float m = lg[r][j];
#pragma unroll
        for (int mask = 1; mask < 16; mask <<= 1) m = fmaxf(m, __shfl_xor(m, mask, 64));
        float ex = __expf(lg[r][j] - m);
        float s = ex;
#pragma unroll
        for (int mask = 1; mask < 16; mask <<= 1) s += __shfl_xor(s, mask, 64);
        size_t b = m0 + w * 32 + i * 16 + q * 4 + r;
        g[b * 64 + j * 16 + m16] = ex / s;
      }
    }
  }
}

// Main: bf16 GEMM C = A x B^T (fp32 acc), relu+bias, Wf-contraction + gating
// in registers (shfl butterfly over the 16 m16-lanes), per-tile partial to
// global partials[nb][t][b] (deterministic; no atomics).
// 128x128 tile, BK=64, PING-PONG double buffer: prefetch tile k+1 into set
// 1-p while MFMAing set p; ONE barrier per K-iter. Each set = two verified
// 128x32 sub-buffers (R9 0-conflict swizzle).
__global__ __launch_bounds__(256, 2) void moe_main_kernel(
    const unsigned short* __restrict__ A,   // x bf16 [B_][K_]
    const unsigned short* __restrict__ Bm,  // We bf16 [N_][K_]
    const float* __restrict__ be,           // [E_*H_] flat == indexed by n
    const float* __restrict__ Wf,           // [T_][H_]
    const float* __restrict__ g,            // [B_][64] (t*16+e)
    float* __restrict__ partials)           // [64 nb][T_][B_]
{
  __shared__ union {
    struct {
      unsigned short A[2][2][128 * 32];  // [set][khalf] 32 KB
      unsigned short B[2][2][128 * 32];  // 32 KB
    } st;
    float allsums[2 * 512];  // reused after K-loop (staging dead)
  } sm;

  const int tid = threadIdx.x;
  const int w = tid >> 6, l = tid & 63;
  const int wm = w >> 1, wn = w & 1;
  const int m16 = l & 15, q = l >> 4;
  const int nb = blockIdx.x, mb = blockIdx.y;
  const size_t m0 = (size_t)mb * 128, n0 = (size_t)nb * 128;

  // staging (per 128x32 sub-buffer): LDS row-major [128][4 chunks of 16B];
  // chunk c of row r at slot c^((r>>1)&3). 2 rows/thread per sub-buffer.
  const int r0s = (w * 2 + 0) * 16 + (l >> 2);
  const int r1s = (w * 2 + 1) * 16 + (l >> 2);
  const int slot = l & 3;
  const int c0 = slot ^ ((r0s >> 1) & 3);
  const int c1 = slot ^ ((r1s >> 1) & 3);
  const size_t offA0 = (m0 + r0s) * K_ + c0 * 8;
  const size_t offA1 = (m0 + r1s) * K_ + c1 * 8;
  const size_t offB0 = (n0 + r0s) * K_ + c0 * 8;
  const size_t offB1 = (n0 + r1s) * K_ + c1 * 8;
  const int l0 = (w * 2 + 0) * 512;  // wave-uniform LDS base (HW adds lane*16)
  const int l1 = (w * 2 + 1) * 512;

  const int arow = wm * 64 + m16;
  const int brow = wn * 64 + m16;
  const int sA = q ^ ((arow >> 1) & 3);  // constant over i: (i*16)>>1 ≡ 0 mod 4
  const int sB = q ^ ((brow >> 1) & 3);

  f32x4 acc[4][4] = {};

  // preload K-tile 0 into set 0
#pragma unroll
  for (int h = 0; h < 2; ++h) {
    gld_lds16(A + offA0 + h * 32, sm.st.A[0][h] + l0);
    gld_lds16(A + offA1 + h * 32, sm.st.A[0][h] + l1);
    gld_lds16(Bm + offB0 + h * 32, sm.st.B[0][h] + l0);
    gld_lds16(Bm + offB1 + h * 32, sm.st.B[0][h] + l1);
  }
  __syncthreads();  // vmcnt(0) drain: tile 0 visible to all waves

  for (int it = 0; it < K_ / 64; ++it) {
    const int p = it & 1;
    const int k0 = it * 64;
    // prefetch next K-tile into the other set (latency hides under MFMA below)
    if (k0 + 64 < K_) {
      const int np = 1 - p;
      const int kn = k0 + 64;
#pragma unroll
      for (int h = 0; h < 2; ++h) {
        gld_lds16(A + offA0 + kn + h * 32, sm.st.A[np][h] + l0);
        gld_lds16(A + offA1 + kn + h * 32, sm.st.A[np][h] + l1);
        gld_lds16(Bm + offB0 + kn + h * 32, sm.st.B[np][h] + l0);
        gld_lds16(Bm + offB1 + kn + h * 32, sm.st.B[np][h] + l1);
      }
    }
    // compute on set p
#pragma unroll
    for (int h = 0; h < 2; ++h) {
      const unsigned short* bufA = sm.st.A[p][h];
      const unsigned short* bufB = sm.st.B[p][h];
      bf16x8 af[4], bfr[4];
#pragma unroll
      for (int i = 0; i < 4; ++i)
        af[i] = *reinterpret_cast<const bf16x8*>(bufA + (arow + i * 16) * 32 + sA * 8);
#pragma unroll
      for (int j = 0; j < 4; ++j)
        bfr[j] = *reinterpret_cast<const bf16x8*>(bufB + (brow + j * 16) * 32 + sB * 8);
#pragma unroll
      for (int i = 0; i < 4; ++i)
#pragma unroll
        for (int j = 0; j < 4; ++j)
          acc[i][j] = __builtin_amdgcn_mfma_f32_16x16x32_bf16(af[i], bfr[j], acc[i][j], 0, 0, 0);
    }
    // one barrier per iter: drains prefetch (vmcnt) + reads (lgkm); next iter
    // may then read set 1-p and overwrite set p.
    __syncthreads();
  }

  const int hbase = (int)(n0 & 511);  // h-offset of this tile (expert = n0>>9)

  // Per-lane epilogue: lane's acc element (i,j,reg) is
  // D[row = wm*64+16i+4q+reg][col = wn*64+16j+m16]  (C/D: col=lane&15, row=4*(lane>>4)+reg)
  float wfv[4][4];  // [t][j]
#pragma unroll
  for (int t = 0; t < 4; ++t)
#pragma unroll
    for (int j = 0; j < 4; ++j)
      wfv[t][j] = Wf[t * H_ + hbase + wn * 64 + j * 16 + m16];
  float bias[4];
#pragma unroll
  for (int j = 0; j < 4; ++j) bias[j] = be[n0 + wn * 64 + j * 16 + m16];

  const int reg_sel = m16 >> 2, t_sel = m16 & 3;  // slot this lane owns after reduce
#pragma unroll
  for (int i = 0; i < 4; ++i) {
    float eo[4][4];  // [j][reg]
#pragma unroll
    for (int j = 0; j < 4; ++j)
#pragma unroll
      for (int r = 0; r < 4; ++r) eo[j][r] = fmaxf(acc[i][j][r] + bias[j], 0.f);
    float p[16];  // [reg*4 + t] partial over this lane's 4 cols
#pragma unroll
    for (int r = 0; r < 4; ++r)
#pragma unroll
      for (int t = 0; t < 4; ++t) {
        float v = 0.f;
#pragma unroll
        for (int j = 0; j < 4; ++j) v += eo[j][r] * wfv[t][j];
        p[r * 4 + t] = v;
      }
    // butterfly-sum over the 16 m16-lanes (same q => same rows, disjoint cols)
#pragma unroll
    for (int mask = 1; mask < 16; mask <<= 1)
#pragma unroll
      for (int s = 0; s < 16; ++s) p[s] += __shfl_xor(p[s], mask, 64);
    // lane keeps slot s = m16
    float v = p[0];
#pragma unroll
    for (int s = 1; s < 16; ++s) v = (m16 == s) ? p[s] : v;
    int row = wm * 64 + i * 16 + q * 4 + reg_sel;
    sm.allsums[wn * 512 + row * 4 + t_sel] = v;
  }
  __syncthreads();

  // combine wn-halves, apply gate, emit per-tile partial (deterministic)
  const int e_idx = (int)(n0 >> 9);
#pragma unroll
  for (int oi = 0; oi < 2; ++oi) {
    int o = tid * 2 + oi;  // 512 = 128 rows x 4 t
    int row = o >> 2, t = o & 3;
    float s = sm.allsums[row * 4 + t] + sm.allsums[512 + row * 4 + t];
    size_t b = m0 + row;
    float gv = g[b * 64 + t * 16 + e_idx];
    partials[(size_t)nb * (T_ * B_) + (size_t)t * B_ + b] = gv * s;
  }
}

// out[t,b] = bf[t] + sum_nb partials[nb][t][b]
__global__ __launch_bounds__(128) void reduce_kernel(const float* __restrict__ partials,
                                                     const float* __restrict__ bfv,
                                                     float* __restrict__ out) {
  int i = blockIdx.x * 128 + threadIdx.x;  // T_*B_ = 32768
  float s = bfv[i >> 13];
#pragma unroll 4
  for (int nb = 0; nb < 64; ++nb) s += partials[(size_t)nb * (T_ * B_) + i];
  out[i] = s;
}

extern "C" void kernel_launch(void* const* d_in, const int* in_sizes, int n_in,
                              void* d_out, int out_size, void* d_ws, size_t ws_size,
                              hipStream_t stream) {
  const float* x = (const float*)d_in[0];   // [B, I]
  const float* We = (const float*)d_in[1];  // [E, H, I]
  const float* be = (const float*)d_in[2];  // [E, H]
  const float* Wg = (const float*)d_in[3];  // [T, E, I]
  const float* bg = (const float*)d_in[4];  // [T, E]
  const float* Wf = (const float*)d_in[5];  // [T, H]
  const float* bf = (const float*)d_in[6];  // [T]
  float* out = (float*)d_out;               // [T, B, 1]

  // ws: xb (16.8MB) | wb (16.8MB) | wgb (0.13MB) | g (2.1MB) | partials (8.4MB)
  unsigned short* xb = (unsigned short*)d_ws;
  unsigned short* wb = xb + (size_t)B_ * K_;
  unsigned short* wgb = wb + (size_t)N_ * K_;
  float* g = (float*)(wgb + (size_t)64 * K_);
  float* partials = g + (size_t)B_ * 64;

  cvt3_kernel<<<(N4X + N4W + N4G + 255) / 256, 256, 0, stream>>>(x, We, Wg, xb, wb, wgb);
  logits_softmax_kernel<<<B_ / 128, 256, 0, stream>>>(xb, wgb, bg, g);
  dim3 grid(N_ / 128, B_ / 128);
  moe_main_kernel<<<grid, 256, 0, stream>>>(xb, wb, be, Wf, g, partials);
  reduce_kernel<<<(T_ * B_) / 128, 128, 0, stream>>>(partials, bf, out);
}

// Round 11
// 274.403 us; speedup vs baseline: 1.1065x; 1.1065x over previous
//
#include <hip/hip_runtime.h>
#include <hip/hip_bf16.h>
#include <stdint.h>

// MMoE: E=16 experts, T=4 tasks, H=512, I=1024, B=8192.
// out[t,b] = sum_e g[b,t,e] * (sum_h relu(x@We^T+be)[b,e,h] * Wf[t,h]) + bf[t]
// R10 finding: ping-pong dbuf (64 KB LDS) regressed — occupancy 31->21.5%
// cost more than 16 fewer barriers saved (confirms m99/m100/m132 on this
// shape). R11: revert to R9's measured-best K-loop (BK=64, two verified
// 32-wide sub-buffers, 32 KB LDS) + compacting fold-exchange butterfly in
// the epilogue (60 ops/i vs naive 143: halve live slots each stage, no
// final select). All else identical to R9.

#define E_ 16
#define T_ 4
#define H_ 512
#define I_ 1024
#define B_ 8192
#define N_ (E_ * H_) /* 8192 */
#define K_ I_        /* 1024 */

typedef __bf16 bf16x8 __attribute__((ext_vector_type(8)));
typedef float f32x4 __attribute__((ext_vector_type(4)));

__device__ __forceinline__ unsigned short f2bf_rne(float f) {
  unsigned int b = __float_as_uint(f);
  b += 0x7fffu + ((b >> 16) & 1u);
  return (unsigned short)(b >> 16);
}

#define N4X (B_ * K_ / 4) /* 2097152 */
#define N4W (N_ * K_ / 4) /* 2097152 */
#define N4G (64 * K_ / 4) /* 16384 */

// merged fp32 -> bf16 (RNE) for x | We | Wg, float4 in / ushort4 out
__global__ __launch_bounds__(256) void cvt3_kernel(const float* __restrict__ x,
                                                   const float* __restrict__ We,
                                                   const float* __restrict__ Wg,
                                                   unsigned short* __restrict__ xb,
                                                   unsigned short* __restrict__ wb,
                                                   unsigned short* __restrict__ wgb) {
  int i = blockIdx.x * 256 + threadIdx.x;
  const float* src;
  unsigned short* dst;
  int j;
  if (i < N4X) {
    src = x; dst = xb; j = i;
  } else if (i < N4X + N4W) {
    src = We; dst = wb; j = i - N4X;
  } else if (i < N4X + N4W + N4G) {
    src = Wg; dst = wgb; j = i - (N4X + N4W);
  } else {
    return;
  }
  float4 v = reinterpret_cast<const float4*>(src)[j];
  ushort4 o;
  o.x = f2bf_rne(v.x);
  o.y = f2bf_rne(v.y);
  o.z = f2bf_rne(v.z);
  o.w = f2bf_rne(v.w);
  reinterpret_cast<ushort4*>(dst)[j] = o;
}

__device__ __forceinline__ void gld_lds16(const void* gp, void* lp) {
  __builtin_amdgcn_global_load_lds((const __attribute__((address_space(1))) void*)gp,
                                   (__attribute__((address_space(3))) void*)lp, 16, 0, 0);
}

// logits L[b][te] = x[b,:]@Wg[te,:] + bg[te] via bf16 MFMA (Wg [T][E][I] is
// already B^T [64][1024]), then softmax over e (= the 16 m16-lanes) in
// registers -> g[b][64]. Tile: M=128, N=64, BK=32; 4 waves x 32 rows each.
__global__ __launch_bounds__(256) void logits_softmax_kernel(
    const unsigned short* __restrict__ A,    // x bf16 [B_][K_]
    const unsigned short* __restrict__ Bm,   // Wg bf16 [64][K_]
    const float* __restrict__ bg,            // [64]
    float* __restrict__ g)                   // [B_][64]
{
  __shared__ struct {
    unsigned short A[128 * 32];  // 8 KB
    unsigned short B[64 * 32];   // 4 KB
  } st;

  const int tid = threadIdx.x;
  const int w = tid >> 6, l = tid & 63;
  const int m16 = l & 15, q = l >> 4;
  const size_t m0 = (size_t)blockIdx.x * 128;

  // A staging: rows w*32..w*32+31, 2 chunks/thread
  const int r0s = (w * 2 + 0) * 16 + (l >> 2);
  const int r1s = (w * 2 + 1) * 16 + (l >> 2);
  const int slot = l & 3;
  const int c0 = slot ^ ((r0s >> 1) & 3);
  const int c1 = slot ^ ((r1s >> 1) & 3);
  const size_t offA0 = (m0 + r0s) * K_ + c0 * 8;
  const size_t offA1 = (m0 + r1s) * K_ + c1 * 8;
  const int l0 = (w * 2 + 0) * 512;
  const int l1 = (w * 2 + 1) * 512;
  // B staging: 64 rows, 1 chunk/thread; wave w covers rows w*16..w*16+15
  const int rBs = w * 16 + (l >> 2);
  const int cB = slot ^ ((rBs >> 1) & 3);
  const size_t offB = (size_t)rBs * K_ + cB * 8;
  const int lB = w * 512;

  const int arow = w * 32 + m16;
  const int sA = q ^ ((arow >> 1) & 3);
  const int sB = q ^ ((m16 >> 1) & 3);

  f32x4 acc[2][4] = {};

  for (int k0 = 0; k0 < K_; k0 += 32) {
    __syncthreads();
    gld_lds16(A + offA0 + k0, st.A + l0);
    gld_lds16(A + offA1 + k0, st.A + l1);
    gld_lds16(Bm + offB + k0, st.B + lB);
    __syncthreads();
    bf16x8 af[2], bfr[4];
#pragma unroll
    for (int i = 0; i < 2; ++i)
      af[i] = *reinterpret_cast<const bf16x8*>(st.A + (arow + i * 16) * 32 + sA * 8);
#pragma unroll
    for (int j = 0; j < 4; ++j)
      bfr[j] = *reinterpret_cast<const bf16x8*>(st.B + (j * 16 + m16) * 32 + sB * 8);
#pragma unroll
    for (int i = 0; i < 2; ++i)
#pragma unroll
      for (int j = 0; j < 4; ++j)
        acc[i][j] = __builtin_amdgcn_mfma_f32_16x16x32_bf16(af[i], bfr[j], acc[i][j], 0, 0, 0);
  }

  // acc[i][j][r] = L[row = w*32+16i+4q+r][te = j*16+m16]; t = j, e = m16.
  float bgv[4];
#pragma unroll
  for (int j = 0; j < 4; ++j) bgv[j] = bg[j * 16 + m16];

#pragma unroll
  for (int i = 0; i < 2; ++i) {
    float lg[4][4];  // [r][j]
#pragma unroll
    for (int j = 0; j < 4; ++j)
#pragma unroll
      for (int r = 0; r < 4; ++r) lg[r][j] = acc[i][j][r] + bgv[j];
#pragma unroll
    for (int r = 0; r < 4; ++r) {
#pragma unroll
      for (int j = 0; j < 4; ++j) {
        float m = lg[r][j];
#pragma unroll
        for (int mask = 1; mask < 16; mask <<= 1) m = fmaxf(m, __shfl_xor(m, mask, 64));
        float ex = __expf(lg[r][j] - m);
        float s = ex;
#pragma unroll
        for (int mask = 1; mask < 16; mask <<= 1) s += __shfl_xor(s, mask, 64);
        size_t b = m0 + w * 32 + i * 16 + q * 4 + r;
        g[b * 64 + j * 16 + m16] = ex / s;
      }
    }
  }
}

// Main: bf16 GEMM C = A x B^T (fp32 acc), relu+bias, Wf-contraction + gating
// in registers (compacting fold-exchange butterfly over the 16 m16-lanes),
// per-tile partial to global partials[nb][t][b] (deterministic; no atomics).
// 128x128 tile, BK=64 as TWO 128x32 buffers with the verified 64B-stride
// staging/swizzle each (0 conflicts) -> 16 barrier-pairs (R9 measured best).
__global__ __launch_bounds__(256, 2) void moe_main_kernel(
    const unsigned short* __restrict__ A,   // x bf16 [B_][K_]
    const unsigned short* __restrict__ Bm,  // We bf16 [N_][K_]
    const float* __restrict__ be,           // [E_*H_] flat == indexed by n
    const float* __restrict__ Wf,           // [T_][H_]
    const float* __restrict__ g,            // [B_][64] (t*16+e)
    float* __restrict__ partials)           // [64 nb][T_][B_]
{
  __shared__ union {
    struct {
      unsigned short A0[128 * 32];
      unsigned short A1[128 * 32];
      unsigned short B0[128 * 32];
      unsigned short B1[128 * 32];
    } st;                    // 32 KB staging (two verified 64B-stride buffers)
    float allsums[2 * 512];  // reused after K-loop (staging dead)
  } sm;

  const int tid = threadIdx.x;
  const int w = tid >> 6, l = tid & 63;
  const int wm = w >> 1, wn = w & 1;
  const int m16 = l & 15, q = l >> 4;
  const int nb = blockIdx.x, mb = blockIdx.y;
  const size_t m0 = (size_t)mb * 128, n0 = (size_t)nb * 128;

  // staging (per 32-wide buffer): LDS row-major [128][4 chunks of 16B];
  // chunk c of row r at slot c^((r>>1)&3). 2 rows/thread per buffer.
  const int r0s = (w * 2 + 0) * 16 + (l >> 2);
  const int r1s = (w * 2 + 1) * 16 + (l >> 2);
  const int slot = l & 3;
  const int c0 = slot ^ ((r0s >> 1) & 3);
  const int c1 = slot ^ ((r1s >> 1) & 3);
  const size_t offA0 = (m0 + r0s) * K_ + c0 * 8;
  const size_t offA1 = (m0 + r1s) * K_ + c1 * 8;
  const size_t offB0 = (n0 + r0s) * K_ + c0 * 8;
  const size_t offB1 = (n0 + r1s) * K_ + c1 * 8;
  const int l0 = (w * 2 + 0) * 512;  // wave-uniform LDS base (HW adds lane*16)
  const int l1 = (w * 2 + 1) * 512;

  const int arow = wm * 64 + m16;
  const int brow = wn * 64 + m16;
  const int sA = q ^ ((arow >> 1) & 3);  // constant over i: (i*16)>>1 ≡ 0 mod 4
  const int sB = q ^ ((brow >> 1) & 3);

  f32x4 acc[4][4] = {};

  for (int k0 = 0; k0 < K_; k0 += 64) {
    __syncthreads();
    // k-half 0 -> buffers A0/B0; k-half 1 (k0+32) -> buffers A1/B1
    gld_lds16(A + offA0 + k0, sm.st.A0 + l0);
    gld_lds16(A + offA1 + k0, sm.st.A0 + l1);
    gld_lds16(A + offA0 + k0 + 32, sm.st.A1 + l0);
    gld_lds16(A + offA1 + k0 + 32, sm.st.A1 + l1);
    gld_lds16(Bm + offB0 + k0, sm.st.B0 + l0);
    gld_lds16(Bm + offB1 + k0, sm.st.B0 + l1);
    gld_lds16(Bm + offB0 + k0 + 32, sm.st.B1 + l0);
    gld_lds16(Bm + offB1 + k0 + 32, sm.st.B1 + l1);
    __syncthreads();  // vmcnt(0) drain before barrier (once per 64-wide K-tile)
#pragma unroll
    for (int h = 0; h < 2; ++h) {
      const unsigned short* bufA = h ? sm.st.A1 : sm.st.A0;
      const unsigned short* bufB = h ? sm.st.B1 : sm.st.B0;
      bf16x8 af[4], bfr[4];
#pragma unroll
      for (int i = 0; i < 4; ++i)
        af[i] = *reinterpret_cast<const bf16x8*>(bufA + (arow + i * 16) * 32 + sA * 8);
#pragma unroll
      for (int j = 0; j < 4; ++j)
        bfr[j] = *reinterpret_cast<const bf16x8*>(bufB + (brow + j * 16) * 32 + sB * 8);
#pragma unroll
      for (int i = 0; i < 4; ++i)
#pragma unroll
        for (int j = 0; j < 4; ++j)
          acc[i][j] = __builtin_amdgcn_mfma_f32_16x16x32_bf16(af[i], bfr[j], acc[i][j], 0, 0, 0);
    }
  }

  __syncthreads();  // staging LDS dead; union'd allsums becomes live

  const int hbase = (int)(n0 & 511);  // h-offset of this tile (expert = n0>>9)

  // Per-lane epilogue: lane's acc element (i,j,reg) is
  // D[row = wm*64+16i+4q+reg][col = wn*64+16j+m16]  (C/D: col=lane&15, row=4*(lane>>4)+reg)
  float wfv[4][4];  // [t][j]
#pragma unroll
  for (int t = 0; t < 4; ++t)
#pragma unroll
    for (int j = 0; j < 4; ++j)
      wfv[t][j] = Wf[t * H_ + hbase + wn * 64 + j * 16 + m16];
  float bias[4];
#pragma unroll
  for (int j = 0; j < 4; ++j) bias[j] = be[n0 + wn * 64 + j * 16 + m16];

  const int b0s = m16 & 1, b1s = (m16 >> 1) & 1, b2s = (m16 >> 2) & 1, b3s = (m16 >> 3) & 1;
#pragma unroll
  for (int i = 0; i < 4; ++i) {
    float eo[4][4];  // [j][reg]
#pragma unroll
    for (int j = 0; j < 4; ++j)
#pragma unroll
      for (int r = 0; r < 4; ++r) eo[j][r] = fmaxf(acc[i][j][r] + bias[j], 0.f);
    float p[16];  // slot s = reg*4 + t, partial over this lane's 4 cols
#pragma unroll
    for (int r = 0; r < 4; ++r)
#pragma unroll
      for (int t = 0; t < 4; ++t) {
        float v = 0.f;
#pragma unroll
        for (int j = 0; j < 4; ++j) v += eo[j][r] * wfv[t][j];
        p[r * 4 + t] = v;
      }
    // Compacting fold-exchange butterfly over the 16 m16-lanes:
    // after stage k, lane holds slots s with low (k+1) bits == m16's;
    // per pair: send partner's keeper, recv, fold into own keeper.
    float q8[8];
#pragma unroll
    for (int m = 0; m < 8; ++m) {  // stage 0 (mask 1): slot bit 0
      float sent = b0s ? p[2 * m] : p[2 * m + 1];
      float recv = __shfl_xor(sent, 1, 64);
      q8[m] = (b0s ? p[2 * m + 1] : p[2 * m]) + recv;  // slot 2m + b0s
    }
    float q4[4];
#pragma unroll
    for (int u = 0; u < 4; ++u) {  // stage 1 (mask 2): slot bit 1
      float sent = b1s ? q8[2 * u] : q8[2 * u + 1];
      float recv = __shfl_xor(sent, 2, 64);
      q4[u] = (b1s ? q8[2 * u + 1] : q8[2 * u]) + recv;  // slot 4u + 2b1s + b0s
    }
    float q2[2];
#pragma unroll
    for (int u = 0; u < 2; ++u) {  // stage 2 (mask 4): slot bit 2
      float sent = b2s ? q4[2 * u] : q4[2 * u + 1];
      float recv = __shfl_xor(sent, 4, 64);
      q2[u] = (b2s ? q4[2 * u + 1] : q4[2 * u]) + recv;  // slot 8u + 4b2s + ...
    }
    // stage 3 (mask 8): slot bit 3
    float sent = b3s ? q2[0] : q2[1];
    float recv = __shfl_xor(sent, 8, 64);
    float v = (b3s ? q2[1] : q2[0]) + recv;  // slot == m16

    int row = wm * 64 + i * 16 + q * 4 + (m16 >> 2);  // reg_sel = m16>>2
    sm.allsums[wn * 512 + row * 4 + (m16 & 3)] = v;   // t_sel = m16&3
  }
  __syncthreads();

  // combine wn-halves, apply gate, emit per-tile partial (deterministic)
  const int e_idx = (int)(n0 >> 9);
#pragma unroll
  for (int oi = 0; oi < 2; ++oi) {
    int o = tid * 2 + oi;  // 512 = 128 rows x 4 t
    int row = o >> 2, t = o & 3;
    float s = sm.allsums[row * 4 + t] + sm.allsums[512 + row * 4 + t];
    size_t b = m0 + row;
    float gv = g[b * 64 + t * 16 + e_idx];
    partials[(size_t)nb * (T_ * B_) + (size_t)t * B_ + b] = gv * s;
  }
}

// out[t,b] = bf[t] + sum_nb partials[nb][t][b]
__global__ __launch_bounds__(128) void reduce_kernel(const float* __restrict__ partials,
                                                     const float* __restrict__ bfv,
                                                     float* __restrict__ out) {
  int i = blockIdx.x * 128 + threadIdx.x;  // T_*B_ = 32768
  float s = bfv[i >> 13];
#pragma unroll 4
  for (int nb = 0; nb < 64; ++nb) s += partials[(size_t)nb * (T_ * B_) + i];
  out[i] = s;
}

extern "C" void kernel_launch(void* const* d_in, const int* in_sizes, int n_in,
                              void* d_out, int out_size, void* d_ws, size_t ws_size,
                              hipStream_t stream) {
  const float* x = (const float*)d_in[0];   // [B, I]
  const float* We = (const float*)d_in[1];  // [E, H, I]
  const float* be = (const float*)d_in[2];  // [E, H]
  const float* Wg = (const float*)d_in[3];  // [T, E, I]
  const float* bg = (const float*)d_in[4];  // [T, E]
  const float* Wf = (const float*)d_in[5];  // [T, H]
  const float* bf = (const float*)d_in[6];  // [T]
  float* out = (float*)d_out;               // [T, B, 1]

  // ws: xb (16.8MB) | wb (16.8MB) | wgb (0.13MB) | g (2.1MB) | partials (8.4MB)
  unsigned short* xb = (unsigned short*)d_ws;
  unsigned short* wb = xb + (size_t)B_ * K_;
  unsigned short* wgb = wb + (size_t)N_ * K_;
  float* g = (float*)(wgb + (size_t)64 * K_);
  float* partials = g + (size_t)B_ * 64;

  cvt3_kernel<<<(N4X + N4W + N4G + 255) / 256, 256, 0, stream>>>(x, We, Wg, xb, wb, wgb);
  logits_softmax_kernel<<<B_ / 128, 256, 0, stream>>>(xb, wgb, bg, g);
  dim3 grid(N_ / 128, B_ / 128);
  moe_main_kernel<<<grid, 256, 0, stream>>>(xb, wb, be, Wf, g, partials);
  reduce_kernel<<<(T_ * B_) / 128, 128, 0, stream>>>(partials, bf, out);
}

// Round 12
// 274.370 us; speedup vs baseline: 1.1066x; 1.0001x over previous
//
#include <hip/hip_runtime.h>
#include <hip/hip_bf16.h>
#include <stdint.h>

// MMoE: E=16 experts, T=4 tasks, H=512, I=1024, B=8192.
// out[t,b] = sum_e g[b,t,e] * (sum_h relu(x@We^T+be)[b,e,h] * Wf[t,h]) + bf[t]
// R11 finding: compacting butterfly -> main 153.5 µs = ~895 TF effective,
// within 2% of the m97-structure HIP ceiling (874-912 TF, m131-m141 show
// source-level K-loop restructuring can't beat it). R12 consolidation:
// direct atomicAdd into out (drop partials+reduce kernel: -8.4MB write,
// -8.4MB read, -1 launch, -tail serialization); out-init folded into cvt3.
// Main K-loop + epilogue + logits byte-identical to R11.

#define E_ 16
#define T_ 4
#define H_ 512
#define I_ 1024
#define B_ 8192
#define N_ (E_ * H_) /* 8192 */
#define K_ I_        /* 1024 */

typedef __bf16 bf16x8 __attribute__((ext_vector_type(8)));
typedef float f32x4 __attribute__((ext_vector_type(4)));

__device__ __forceinline__ unsigned short f2bf_rne(float f) {
  unsigned int b = __float_as_uint(f);
  b += 0x7fffu + ((b >> 16) & 1u);
  return (unsigned short)(b >> 16);
}

#define N4X (B_ * K_ / 4) /* 2097152 */
#define N4W (N_ * K_ / 4) /* 2097152 */
#define N4G (64 * K_ / 4) /* 16384 */

// merged fp32 -> bf16 (RNE) for x | We | Wg, float4 in / ushort4 out.
// First T_*B_ threads also initialize out[t*B+b] = bf[t] (atomic-accumulated
// by moe_main later; harness re-poisons out before every launch).
__global__ __launch_bounds__(256) void cvt3_kernel(const float* __restrict__ x,
                                                   const float* __restrict__ We,
                                                   const float* __restrict__ Wg,
                                                   const float* __restrict__ bfv,
                                                   unsigned short* __restrict__ xb,
                                                   unsigned short* __restrict__ wb,
                                                   unsigned short* __restrict__ wgb,
                                                   float* __restrict__ out) {
  int i = blockIdx.x * 256 + threadIdx.x;
  if (i < T_ * B_) out[i] = bfv[i >> 13];  // t = i / 8192
  const float* src;
  unsigned short* dst;
  int j;
  if (i < N4X) {
    src = x; dst = xb; j = i;
  } else if (i < N4X + N4W) {
    src = We; dst = wb; j = i - N4X;
  } else if (i < N4X + N4W + N4G) {
    src = Wg; dst = wgb; j = i - (N4X + N4W);
  } else {
    return;
  }
  float4 v = reinterpret_cast<const float4*>(src)[j];
  ushort4 o;
  o.x = f2bf_rne(v.x);
  o.y = f2bf_rne(v.y);
  o.z = f2bf_rne(v.z);
  o.w = f2bf_rne(v.w);
  reinterpret_cast<ushort4*>(dst)[j] = o;
}

__device__ __forceinline__ void gld_lds16(const void* gp, void* lp) {
  __builtin_amdgcn_global_load_lds((const __attribute__((address_space(1))) void*)gp,
                                   (__attribute__((address_space(3))) void*)lp, 16, 0, 0);
}

// logits L[b][te] = x[b,:]@Wg[te,:] + bg[te] via bf16 MFMA (Wg [T][E][I] is
// already B^T [64][1024]), then softmax over e (= the 16 m16-lanes) in
// registers -> g[b][64]. Tile: M=128, N=64, BK=32; 4 waves x 32 rows each.
__global__ __launch_bounds__(256) void logits_softmax_kernel(
    const unsigned short* __restrict__ A,    // x bf16 [B_][K_]
    const unsigned short* __restrict__ Bm,   // Wg bf16 [64][K_]
    const float* __restrict__ bg,            // [64]
    float* __restrict__ g)                   // [B_][64]
{
  __shared__ struct {
    unsigned short A[128 * 32];  // 8 KB
    unsigned short B[64 * 32];   // 4 KB
  } st;

  const int tid = threadIdx.x;
  const int w = tid >> 6, l = tid & 63;
  const int m16 = l & 15, q = l >> 4;
  const size_t m0 = (size_t)blockIdx.x * 128;

  // A staging: rows w*32..w*32+31, 2 chunks/thread
  const int r0s = (w * 2 + 0) * 16 + (l >> 2);
  const int r1s = (w * 2 + 1) * 16 + (l >> 2);
  const int slot = l & 3;
  const int c0 = slot ^ ((r0s >> 1) & 3);
  const int c1 = slot ^ ((r1s >> 1) & 3);
  const size_t offA0 = (m0 + r0s) * K_ + c0 * 8;
  const size_t offA1 = (m0 + r1s) * K_ + c1 * 8;
  const int l0 = (w * 2 + 0) * 512;
  const int l1 = (w * 2 + 1) * 512;
  // B staging: 64 rows, 1 chunk/thread; wave w covers rows w*16..w*16+15
  const int rBs = w * 16 + (l >> 2);
  const int cB = slot ^ ((rBs >> 1) & 3);
  const size_t offB = (size_t)rBs * K_ + cB * 8;
  const int lB = w * 512;

  const int arow = w * 32 + m16;
  const int sA = q ^ ((arow >> 1) & 3);
  const int sB = q ^ ((m16 >> 1) & 3);

  f32x4 acc[2][4] = {};

  for (int k0 = 0; k0 < K_; k0 += 32) {
    __syncthreads();
    gld_lds16(A + offA0 + k0, st.A + l0);
    gld_lds16(A + offA1 + k0, st.A + l1);
    gld_lds16(Bm + offB + k0, st.B + lB);
    __syncthreads();
    bf16x8 af[2], bfr[4];
#pragma unroll
    for (int i = 0; i < 2; ++i)
      af[i] = *reinterpret_cast<const bf16x8*>(st.A + (arow + i * 16) * 32 + sA * 8);
#pragma unroll
    for (int j = 0; j < 4; ++j)
      bfr[j] = *reinterpret_cast<const bf16x8*>(st.B + (j * 16 + m16) * 32 + sB * 8);
#pragma unroll
    for (int i = 0; i < 2; ++i)
#pragma unroll
      for (int j = 0; j < 4; ++j)
        acc[i][j] = __builtin_amdgcn_mfma_f32_16x16x32_bf16(af[i], bfr[j], acc[i][j], 0, 0, 0);
  }

  // acc[i][j][r] = L[row = w*32+16i+4q+r][te = j*16+m16]; t = j, e = m16.
  float bgv[4];
#pragma unroll
  for (int j = 0; j < 4; ++j) bgv[j] = bg[j * 16 + m16];

#pragma unroll
  for (int i = 0; i < 2; ++i) {
    float lg[4][4];  // [r][j]
#pragma unroll
    for (int j = 0; j < 4; ++j)
#pragma unroll
      for (int r = 0; r < 4; ++r) lg[r][j] = acc[i][j][r] + bgv[j];
#pragma unroll
    for (int r = 0; r < 4; ++r) {
#pragma unroll
      for (int j = 0; j < 4; ++j) {
        float m = lg[r][j];
#pragma unroll
        for (int mask = 1; mask < 16; mask <<= 1) m = fmaxf(m, __shfl_xor(m, mask, 64));
        float ex = __expf(lg[r][j] - m);
        float s = ex;
#pragma unroll
        for (int mask = 1; mask < 16; mask <<= 1) s += __shfl_xor(s, mask, 64);
        size_t b = m0 + w * 32 + i * 16 + q * 4 + r;
        g[b * 64 + j * 16 + m16] = ex / s;
      }
    }
  }
}

// Main: bf16 GEMM C = A x B^T (fp32 acc), relu+bias, Wf-contraction + gating
// in registers (compacting fold-exchange butterfly over the 16 m16-lanes),
// then atomicAdd of the gated per-tile partial directly into out[t][b].
// 128x128 tile, BK=64 as TWO 128x32 buffers with the verified 64B-stride
// staging/swizzle each (0 conflicts) -> 16 barrier-pairs (R9 measured best).
__global__ __launch_bounds__(256, 2) void moe_main_kernel(
    const unsigned short* __restrict__ A,   // x bf16 [B_][K_]
    const unsigned short* __restrict__ Bm,  // We bf16 [N_][K_]
    const float* __restrict__ be,           // [E_*H_] flat == indexed by n
    const float* __restrict__ Wf,           // [T_][H_]
    const float* __restrict__ g,            // [B_][64] (t*16+e)
    float* __restrict__ out)                // [T_][B_] (pre-init to bf[t])
{
  __shared__ union {
    struct {
      unsigned short A0[128 * 32];
      unsigned short A1[128 * 32];
      unsigned short B0[128 * 32];
      unsigned short B1[128 * 32];
    } st;                    // 32 KB staging (two verified 64B-stride buffers)
    float allsums[2 * 512];  // reused after K-loop (staging dead)
  } sm;

  const int tid = threadIdx.x;
  const int w = tid >> 6, l = tid & 63;
  const int wm = w >> 1, wn = w & 1;
  const int m16 = l & 15, q = l >> 4;
  const int nb = blockIdx.x, mb = blockIdx.y;
  const size_t m0 = (size_t)mb * 128, n0 = (size_t)nb * 128;

  // staging (per 32-wide buffer): LDS row-major [128][4 chunks of 16B];
  // chunk c of row r at slot c^((r>>1)&3). 2 rows/thread per buffer.
  const int r0s = (w * 2 + 0) * 16 + (l >> 2);
  const int r1s = (w * 2 + 1) * 16 + (l >> 2);
  const int slot = l & 3;
  const int c0 = slot ^ ((r0s >> 1) & 3);
  const int c1 = slot ^ ((r1s >> 1) & 3);
  const size_t offA0 = (m0 + r0s) * K_ + c0 * 8;
  const size_t offA1 = (m0 + r1s) * K_ + c1 * 8;
  const size_t offB0 = (n0 + r0s) * K_ + c0 * 8;
  const size_t offB1 = (n0 + r1s) * K_ + c1 * 8;
  const int l0 = (w * 2 + 0) * 512;  // wave-uniform LDS base (HW adds lane*16)
  const int l1 = (w * 2 + 1) * 512;

  const int arow = wm * 64 + m16;
  const int brow = wn * 64 + m16;
  const int sA = q ^ ((arow >> 1) & 3);  // constant over i: (i*16)>>1 ≡ 0 mod 4
  const int sB = q ^ ((brow >> 1) & 3);

  f32x4 acc[4][4] = {};

  for (int k0 = 0; k0 < K_; k0 += 64) {
    __syncthreads();
    // k-half 0 -> buffers A0/B0; k-half 1 (k0+32) -> buffers A1/B1
    gld_lds16(A + offA0 + k0, sm.st.A0 + l0);
    gld_lds16(A + offA1 + k0, sm.st.A0 + l1);
    gld_lds16(A + offA0 + k0 + 32, sm.st.A1 + l0);
    gld_lds16(A + offA1 + k0 + 32, sm.st.A1 + l1);
    gld_lds16(Bm + offB0 + k0, sm.st.B0 + l0);
    gld_lds16(Bm + offB1 + k0, sm.st.B0 + l1);
    gld_lds16(Bm + offB0 + k0 + 32, sm.st.B1 + l0);
    gld_lds16(Bm + offB1 + k0 + 32, sm.st.B1 + l1);
    __syncthreads();  // vmcnt(0) drain before barrier (once per 64-wide K-tile)
#pragma unroll
    for (int h = 0; h < 2; ++h) {
      const unsigned short* bufA = h ? sm.st.A1 : sm.st.A0;
      const unsigned short* bufB = h ? sm.st.B1 : sm.st.B0;
      bf16x8 af[4], bfr[4];
#pragma unroll
      for (int i = 0; i < 4; ++i)
        af[i] = *reinterpret_cast<const bf16x8*>(bufA + (arow + i * 16) * 32 + sA * 8);
#pragma unroll
      for (int j = 0; j < 4; ++j)
        bfr[j] = *reinterpret_cast<const bf16x8*>(bufB + (brow + j * 16) * 32 + sB * 8);
#pragma unroll
      for (int i = 0; i < 4; ++i)
#pragma unroll
        for (int j = 0; j < 4; ++j)
          acc[i][j] = __builtin_amdgcn_mfma_f32_16x16x32_bf16(af[i], bfr[j], acc[i][j], 0, 0, 0);
    }
  }

  __syncthreads();  // staging LDS dead; union'd allsums becomes live

  const int hbase = (int)(n0 & 511);  // h-offset of this tile (expert = n0>>9)

  // Per-lane epilogue: lane's acc element (i,j,reg) is
  // D[row = wm*64+16i+4q+reg][col = wn*64+16j+m16]  (C/D: col=lane&15, row=4*(lane>>4)+reg)
  float wfv[4][4];  // [t][j]
#pragma unroll
  for (int t = 0; t < 4; ++t)
#pragma unroll
    for (int j = 0; j < 4; ++j)
      wfv[t][j] = Wf[t * H_ + hbase + wn * 64 + j * 16 + m16];
  float bias[4];
#pragma unroll
  for (int j = 0; j < 4; ++j) bias[j] = be[n0 + wn * 64 + j * 16 + m16];

  const int b0s = m16 & 1, b1s = (m16 >> 1) & 1, b2s = (m16 >> 2) & 1, b3s = (m16 >> 3) & 1;
#pragma unroll
  for (int i = 0; i < 4; ++i) {
    float eo[4][4];  // [j][reg]
#pragma unroll
    for (int j = 0; j < 4; ++j)
#pragma unroll
      for (int r = 0; r < 4; ++r) eo[j][r] = fmaxf(acc[i][j][r] + bias[j], 0.f);
    float p[16];  // slot s = reg*4 + t, partial over this lane's 4 cols
#pragma unroll
    for (int r = 0; r < 4; ++r)
#pragma unroll
      for (int t = 0; t < 4; ++t) {
        float v = 0.f;
#pragma unroll
        for (int j = 0; j < 4; ++j) v += eo[j][r] * wfv[t][j];
        p[r * 4 + t] = v;
      }
    // Compacting fold-exchange butterfly over the 16 m16-lanes:
    // after stage k, lane holds slots s with low (k+1) bits == m16's;
    // per pair: send partner's keeper, recv, fold into own keeper.
    float q8[8];
#pragma unroll
    for (int m = 0; m < 8; ++m) {  // stage 0 (mask 1): slot bit 0
      float sent = b0s ? p[2 * m] : p[2 * m + 1];
      float recv = __shfl_xor(sent, 1, 64);
      q8[m] = (b0s ? p[2 * m + 1] : p[2 * m]) + recv;  // slot 2m + b0s
    }
    float q4[4];
#pragma unroll
    for (int u = 0; u < 4; ++u) {  // stage 1 (mask 2): slot bit 1
      float sent = b1s ? q8[2 * u] : q8[2 * u + 1];
      float recv = __shfl_xor(sent, 2, 64);
      q4[u] = (b1s ? q8[2 * u + 1] : q8[2 * u]) + recv;  // slot 4u + 2b1s + b0s
    }
    float q2[2];
#pragma unroll
    for (int u = 0; u < 2; ++u) {  // stage 2 (mask 4): slot bit 2
      float sent = b2s ? q4[2 * u] : q4[2 * u + 1];
      float recv = __shfl_xor(sent, 4, 64);
      q2[u] = (b2s ? q4[2 * u + 1] : q4[2 * u]) + recv;  // slot 8u + 4b2s + ...
    }
    // stage 3 (mask 8): slot bit 3
    float sent = b3s ? q2[0] : q2[1];
    float recv = __shfl_xor(sent, 8, 64);
    float v = (b3s ? q2[1] : q2[0]) + recv;  // slot == m16

    int row = wm * 64 + i * 16 + q * 4 + (m16 >> 2);  // reg_sel = m16>>2
    sm.allsums[wn * 512 + row * 4 + (m16 & 3)] = v;   // t_sel = m16&3
  }
  __syncthreads();

  // combine wn-halves, apply gate, atomic-accumulate into out (device-scope)
  const int e_idx = (int)(n0 >> 9);
#pragma unroll
  for (int oi = 0; oi < 2; ++oi) {
    int o = tid * 2 + oi;  // 512 = 128 rows x 4 t
    int row = o >> 2, t = o & 3;
    float s = sm.allsums[row * 4 + t] + sm.allsums[512 + row * 4 + t];
    size_t b = m0 + row;
    float gv = g[b * 64 + t * 16 + e_idx];
    atomicAdd(&out[(size_t)t * B_ + b], gv * s);
  }
}

extern "C" void kernel_launch(void* const* d_in, const int* in_sizes, int n_in,
                              void* d_out, int out_size, void* d_ws, size_t ws_size,
                              hipStream_t stream) {
  const float* x = (const float*)d_in[0];   // [B, I]
  const float* We = (const float*)d_in[1];  // [E, H, I]
  const float* be = (const float*)d_in[2];  // [E, H]
  const float* Wg = (const float*)d_in[3];  // [T, E, I]
  const float* bg = (const float*)d_in[4];  // [T, E]
  const float* Wf = (const float*)d_in[5];  // [T, H]
  const float* bf = (const float*)d_in[6];  // [T]
  float* out = (float*)d_out;               // [T, B, 1]

  // ws: xb (16.8MB) | wb (16.8MB) | wgb (0.13MB) | g (2.1MB)
  unsigned short* xb = (unsigned short*)d_ws;
  unsigned short* wb = xb + (size_t)B_ * K_;
  unsigned short* wgb = wb + (size_t)N_ * K_;
  float* g = (float*)(wgb + (size_t)64 * K_);

  cvt3_kernel<<<(N4X + N4W + N4G + 255) / 256, 256, 0, stream>>>(x, We, Wg, bf, xb, wb, wgb, out);
  logits_softmax_kernel<<<B_ / 128, 256, 0, stream>>>(xb, wgb, bg, g);
  dim3 grid(N_ / 128, B_ / 128);
  moe_main_kernel<<<grid, 256, 0, stream>>>(xb, wb, be, Wf, g, out);
}

// Round 13
// 263.624 us; speedup vs baseline: 1.1517x; 1.0408x over previous
//
#include <hip/hip_runtime.h>
#include <hip/hip_bf16.h>
#include <stdint.h>

// MMoE: E=16 experts, T=4 tasks, H=512, I=1024, B=8192.
// out[t,b] = sum_e g[b,t,e] * (sum_h relu(x@We^T+be)[b,e,h] * Wf[t,h]) + bf[t]
// R12 finding: atomicAdd into out cost main +9 µs — grid had blockIdx.x=nb,
// so the 64 concurrently-dispatched blocks shared one mb and their epilogue
// atomics collided on the SAME 512 addresses (64-deep L2 RMW serialization).
// R13: swap grid mapping (blockIdx.x=mb, blockIdx.y=nb) -> concurrent blocks
// hit disjoint out addresses. All else byte-identical to R12.

#define E_ 16
#define T_ 4
#define H_ 512
#define I_ 1024
#define B_ 8192
#define N_ (E_ * H_) /* 8192 */
#define K_ I_        /* 1024 */

typedef __bf16 bf16x8 __attribute__((ext_vector_type(8)));
typedef float f32x4 __attribute__((ext_vector_type(4)));

__device__ __forceinline__ unsigned short f2bf_rne(float f) {
  unsigned int b = __float_as_uint(f);
  b += 0x7fffu + ((b >> 16) & 1u);
  return (unsigned short)(b >> 16);
}

#define N4X (B_ * K_ / 4) /* 2097152 */
#define N4W (N_ * K_ / 4) /* 2097152 */
#define N4G (64 * K_ / 4) /* 16384 */

// merged fp32 -> bf16 (RNE) for x | We | Wg, float4 in / ushort4 out.
// First T_*B_ threads also initialize out[t*B+b] = bf[t] (atomic-accumulated
// by moe_main later; harness re-poisons out before every launch).
__global__ __launch_bounds__(256) void cvt3_kernel(const float* __restrict__ x,
                                                   const float* __restrict__ We,
                                                   const float* __restrict__ Wg,
                                                   const float* __restrict__ bfv,
                                                   unsigned short* __restrict__ xb,
                                                   unsigned short* __restrict__ wb,
                                                   unsigned short* __restrict__ wgb,
                                                   float* __restrict__ out) {
  int i = blockIdx.x * 256 + threadIdx.x;
  if (i < T_ * B_) out[i] = bfv[i >> 13];  // t = i / 8192
  const float* src;
  unsigned short* dst;
  int j;
  if (i < N4X) {
    src = x; dst = xb; j = i;
  } else if (i < N4X + N4W) {
    src = We; dst = wb; j = i - N4X;
  } else if (i < N4X + N4W + N4G) {
    src = Wg; dst = wgb; j = i - (N4X + N4W);
  } else {
    return;
  }
  float4 v = reinterpret_cast<const float4*>(src)[j];
  ushort4 o;
  o.x = f2bf_rne(v.x);
  o.y = f2bf_rne(v.y);
  o.z = f2bf_rne(v.z);
  o.w = f2bf_rne(v.w);
  reinterpret_cast<ushort4*>(dst)[j] = o;
}

__device__ __forceinline__ void gld_lds16(const void* gp, void* lp) {
  __builtin_amdgcn_global_load_lds((const __attribute__((address_space(1))) void*)gp,
                                   (__attribute__((address_space(3))) void*)lp, 16, 0, 0);
}

// logits L[b][te] = x[b,:]@Wg[te,:] + bg[te] via bf16 MFMA (Wg [T][E][I] is
// already B^T [64][1024]), then softmax over e (= the 16 m16-lanes) in
// registers -> g[b][64]. Tile: M=128, N=64, BK=32; 4 waves x 32 rows each.
__global__ __launch_bounds__(256) void logits_softmax_kernel(
    const unsigned short* __restrict__ A,    // x bf16 [B_][K_]
    const unsigned short* __restrict__ Bm,   // Wg bf16 [64][K_]
    const float* __restrict__ bg,            // [64]
    float* __restrict__ g)                   // [B_][64]
{
  __shared__ struct {
    unsigned short A[128 * 32];  // 8 KB
    unsigned short B[64 * 32];   // 4 KB
  } st;

  const int tid = threadIdx.x;
  const int w = tid >> 6, l = tid & 63;
  const int m16 = l & 15, q = l >> 4;
  const size_t m0 = (size_t)blockIdx.x * 128;

  // A staging: rows w*32..w*32+31, 2 chunks/thread
  const int r0s = (w * 2 + 0) * 16 + (l >> 2);
  const int r1s = (w * 2 + 1) * 16 + (l >> 2);
  const int slot = l & 3;
  const int c0 = slot ^ ((r0s >> 1) & 3);
  const int c1 = slot ^ ((r1s >> 1) & 3);
  const size_t offA0 = (m0 + r0s) * K_ + c0 * 8;
  const size_t offA1 = (m0 + r1s) * K_ + c1 * 8;
  const int l0 = (w * 2 + 0) * 512;
  const int l1 = (w * 2 + 1) * 512;
  // B staging: 64 rows, 1 chunk/thread; wave w covers rows w*16..w*16+15
  const int rBs = w * 16 + (l >> 2);
  const int cB = slot ^ ((rBs >> 1) & 3);
  const size_t offB = (size_t)rBs * K_ + cB * 8;
  const int lB = w * 512;

  const int arow = w * 32 + m16;
  const int sA = q ^ ((arow >> 1) & 3);
  const int sB = q ^ ((m16 >> 1) & 3);

  f32x4 acc[2][4] = {};

  for (int k0 = 0; k0 < K_; k0 += 32) {
    __syncthreads();
    gld_lds16(A + offA0 + k0, st.A + l0);
    gld_lds16(A + offA1 + k0, st.A + l1);
    gld_lds16(Bm + offB + k0, st.B + lB);
    __syncthreads();
    bf16x8 af[2], bfr[4];
#pragma unroll
    for (int i = 0; i < 2; ++i)
      af[i] = *reinterpret_cast<const bf16x8*>(st.A + (arow + i * 16) * 32 + sA * 8);
#pragma unroll
    for (int j = 0; j < 4; ++j)
      bfr[j] = *reinterpret_cast<const bf16x8*>(st.B + (j * 16 + m16) * 32 + sB * 8);
#pragma unroll
    for (int i = 0; i < 2; ++i)
#pragma unroll
      for (int j = 0; j < 4; ++j)
        acc[i][j] = __builtin_amdgcn_mfma_f32_16x16x32_bf16(af[i], bfr[j], acc[i][j], 0, 0, 0);
  }

  // acc[i][j][r] = L[row = w*32+16i+4q+r][te = j*16+m16]; t = j, e = m16.
  float bgv[4];
#pragma unroll
  for (int j = 0; j < 4; ++j) bgv[j] = bg[j * 16 + m16];

#pragma unroll
  for (int i = 0; i < 2; ++i) {
    float lg[4][4];  // [r][j]
#pragma unroll
    for (int j = 0; j < 4; ++j)
#pragma unroll
      for (int r = 0; r < 4; ++r) lg[r][j] = acc[i][j][r] + bgv[j];
#pragma unroll
    for (int r = 0; r < 4; ++r) {
#pragma unroll
      for (int j = 0; j < 4; ++j) {
        float m = lg[r][j];
#pragma unroll
        for (int mask = 1; mask < 16; mask <<= 1) m = fmaxf(m, __shfl_xor(m, mask, 64));
        float ex = __expf(lg[r][j] - m);
        float s = ex;
#pragma unroll
        for (int mask = 1; mask < 16; mask <<= 1) s += __shfl_xor(s, mask, 64);
        size_t b = m0 + w * 32 + i * 16 + q * 4 + r;
        g[b * 64 + j * 16 + m16] = ex / s;
      }
    }
  }
}

// Main: bf16 GEMM C = A x B^T (fp32 acc), relu+bias, Wf-contraction + gating
// in registers (compacting fold-exchange butterfly over the 16 m16-lanes),
// then atomicAdd of the gated per-tile partial directly into out[t][b].
// 128x128 tile, BK=64 as TWO 128x32 buffers with the verified 64B-stride
// staging/swizzle each (0 conflicts) -> 16 barrier-pairs (R9 measured best).
// Grid: blockIdx.x = mb (concurrent blocks -> disjoint out rows, no atomic
// collision), blockIdx.y = nb.
__global__ __launch_bounds__(256, 2) void moe_main_kernel(
    const unsigned short* __restrict__ A,   // x bf16 [B_][K_]
    const unsigned short* __restrict__ Bm,  // We bf16 [N_][K_]
    const float* __restrict__ be,           // [E_*H_] flat == indexed by n
    const float* __restrict__ Wf,           // [T_][H_]
    const float* __restrict__ g,            // [B_][64] (t*16+e)
    float* __restrict__ out)                // [T_][B_] (pre-init to bf[t])
{
  __shared__ union {
    struct {
      unsigned short A0[128 * 32];
      unsigned short A1[128 * 32];
      unsigned short B0[128 * 32];
      unsigned short B1[128 * 32];
    } st;                    // 32 KB staging (two verified 64B-stride buffers)
    float allsums[2 * 512];  // reused after K-loop (staging dead)
  } sm;

  const int tid = threadIdx.x;
  const int w = tid >> 6, l = tid & 63;
  const int wm = w >> 1, wn = w & 1;
  const int m16 = l & 15, q = l >> 4;
  const int mb = blockIdx.x, nb = blockIdx.y;  // x=mb: decorrelate atomics
  const size_t m0 = (size_t)mb * 128, n0 = (size_t)nb * 128;

  // staging (per 32-wide buffer): LDS row-major [128][4 chunks of 16B];
  // chunk c of row r at slot c^((r>>1)&3). 2 rows/thread per buffer.
  const int r0s = (w * 2 + 0) * 16 + (l >> 2);
  const int r1s = (w * 2 + 1) * 16 + (l >> 2);
  const int slot = l & 3;
  const int c0 = slot ^ ((r0s >> 1) & 3);
  const int c1 = slot ^ ((r1s >> 1) & 3);
  const size_t offA0 = (m0 + r0s) * K_ + c0 * 8;
  const size_t offA1 = (m0 + r1s) * K_ + c1 * 8;
  const size_t offB0 = (n0 + r0s) * K_ + c0 * 8;
  const size_t offB1 = (n0 + r1s) * K_ + c1 * 8;
  const int l0 = (w * 2 + 0) * 512;  // wave-uniform LDS base (HW adds lane*16)
  const int l1 = (w * 2 + 1) * 512;

  const int arow = wm * 64 + m16;
  const int brow = wn * 64 + m16;
  const int sA = q ^ ((arow >> 1) & 3);  // constant over i: (i*16)>>1 ≡ 0 mod 4
  const int sB = q ^ ((brow >> 1) & 3);

  f32x4 acc[4][4] = {};

  for (int k0 = 0; k0 < K_; k0 += 64) {
    __syncthreads();
    // k-half 0 -> buffers A0/B0; k-half 1 (k0+32) -> buffers A1/B1
    gld_lds16(A + offA0 + k0, sm.st.A0 + l0);
    gld_lds16(A + offA1 + k0, sm.st.A0 + l1);
    gld_lds16(A + offA0 + k0 + 32, sm.st.A1 + l0);
    gld_lds16(A + offA1 + k0 + 32, sm.st.A1 + l1);
    gld_lds16(Bm + offB0 + k0, sm.st.B0 + l0);
    gld_lds16(Bm + offB1 + k0, sm.st.B0 + l1);
    gld_lds16(Bm + offB0 + k0 + 32, sm.st.B1 + l0);
    gld_lds16(Bm + offB1 + k0 + 32, sm.st.B1 + l1);
    __syncthreads();  // vmcnt(0) drain before barrier (once per 64-wide K-tile)
#pragma unroll
    for (int h = 0; h < 2; ++h) {
      const unsigned short* bufA = h ? sm.st.A1 : sm.st.A0;
      const unsigned short* bufB = h ? sm.st.B1 : sm.st.B0;
      bf16x8 af[4], bfr[4];
#pragma unroll
      for (int i = 0; i < 4; ++i)
        af[i] = *reinterpret_cast<const bf16x8*>(bufA + (arow + i * 16) * 32 + sA * 8);
#pragma unroll
      for (int j = 0; j < 4; ++j)
        bfr[j] = *reinterpret_cast<const bf16x8*>(bufB + (brow + j * 16) * 32 + sB * 8);
#pragma unroll
      for (int i = 0; i < 4; ++i)
#pragma unroll
        for (int j = 0; j < 4; ++j)
          acc[i][j] = __builtin_amdgcn_mfma_f32_16x16x32_bf16(af[i], bfr[j], acc[i][j], 0, 0, 0);
    }
  }

  __syncthreads();  // staging LDS dead; union'd allsums becomes live

  const int hbase = (int)(n0 & 511);  // h-offset of this tile (expert = n0>>9)

  // Per-lane epilogue: lane's acc element (i,j,reg) is
  // D[row = wm*64+16i+4q+reg][col = wn*64+16j+m16]  (C/D: col=lane&15, row=4*(lane>>4)+reg)
  float wfv[4][4];  // [t][j]
#pragma unroll
  for (int t = 0; t < 4; ++t)
#pragma unroll
    for (int j = 0; j < 4; ++j)
      wfv[t][j] = Wf[t * H_ + hbase + wn * 64 + j * 16 + m16];
  float bias[4];
#pragma unroll
  for (int j = 0; j < 4; ++j) bias[j] = be[n0 + wn * 64 + j * 16 + m16];

  const int b0s = m16 & 1, b1s = (m16 >> 1) & 1, b2s = (m16 >> 2) & 1, b3s = (m16 >> 3) & 1;
#pragma unroll
  for (int i = 0; i < 4; ++i) {
    float eo[4][4];  // [j][reg]
#pragma unroll
    for (int j = 0; j < 4; ++j)
#pragma unroll
      for (int r = 0; r < 4; ++r) eo[j][r] = fmaxf(acc[i][j][r] + bias[j], 0.f);
    float p[16];  // slot s = reg*4 + t, partial over this lane's 4 cols
#pragma unroll
    for (int r = 0; r < 4; ++r)
#pragma unroll
      for (int t = 0; t < 4; ++t) {
        float v = 0.f;
#pragma unroll
        for (int j = 0; j < 4; ++j) v += eo[j][r] * wfv[t][j];
        p[r * 4 + t] = v;
      }
    // Compacting fold-exchange butterfly over the 16 m16-lanes:
    // after stage k, lane holds slots s with low (k+1) bits == m16's;
    // per pair: send partner's keeper, recv, fold into own keeper.
    float q8[8];
#pragma unroll
    for (int m = 0; m < 8; ++m) {  // stage 0 (mask 1): slot bit 0
      float sent = b0s ? p[2 * m] : p[2 * m + 1];
      float recv = __shfl_xor(sent, 1, 64);
      q8[m] = (b0s ? p[2 * m + 1] : p[2 * m]) + recv;  // slot 2m + b0s
    }
    float q4[4];
#pragma unroll
    for (int u = 0; u < 4; ++u) {  // stage 1 (mask 2): slot bit 1
      float sent = b1s ? q8[2 * u] : q8[2 * u + 1];
      float recv = __shfl_xor(sent, 2, 64);
      q4[u] = (b1s ? q8[2 * u + 1] : q8[2 * u]) + recv;  // slot 4u + 2b1s + b0s
    }
    float q2[2];
#pragma unroll
    for (int u = 0; u < 2; ++u) {  // stage 2 (mask 4): slot bit 2
      float sent = b2s ? q4[2 * u] : q4[2 * u + 1];
      float recv = __shfl_xor(sent, 4, 64);
      q2[u] = (b2s ? q4[2 * u + 1] : q4[2 * u]) + recv;  // slot 8u + 4b2s + ...
    }
    // stage 3 (mask 8): slot bit 3
    float sent = b3s ? q2[0] : q2[1];
    float recv = __shfl_xor(sent, 8, 64);
    float v = (b3s ? q2[1] : q2[0]) + recv;  // slot == m16

    int row = wm * 64 + i * 16 + q * 4 + (m16 >> 2);  // reg_sel = m16>>2
    sm.allsums[wn * 512 + row * 4 + (m16 & 3)] = v;   // t_sel = m16&3
  }
  __syncthreads();

  // combine wn-halves, apply gate, atomic-accumulate into out (device-scope)
  const int e_idx = (int)(n0 >> 9);
#pragma unroll
  for (int oi = 0; oi < 2; ++oi) {
    int o = tid * 2 + oi;  // 512 = 128 rows x 4 t
    int row = o >> 2, t = o & 3;
    float s = sm.allsums[row * 4 + t] + sm.allsums[512 + row * 4 + t];
    size_t b = m0 + row;
    float gv = g[b * 64 + t * 16 + e_idx];
    atomicAdd(&out[(size_t)t * B_ + b], gv * s);
  }
}

extern "C" void kernel_launch(void* const* d_in, const int* in_sizes, int n_in,
                              void* d_out, int out_size, void* d_ws, size_t ws_size,
                              hipStream_t stream) {
  const float* x = (const float*)d_in[0];   // [B, I]
  const float* We = (const float*)d_in[1];  // [E, H, I]
  const float* be = (const float*)d_in[2];  // [E, H]
  const float* Wg = (const float*)d_in[3];  // [T, E, I]
  const float* bg = (const float*)d_in[4];  // [T, E]
  const float* Wf = (const float*)d_in[5];  // [T, H]
  const float* bf = (const float*)d_in[6];  // [T]
  float* out = (float*)d_out;               // [T, B, 1]

  // ws: xb (16.8MB) | wb (16.8MB) | wgb (0.13MB) | g (2.1MB)
  unsigned short* xb = (unsigned short*)d_ws;
  unsigned short* wb = xb + (size_t)B_ * K_;
  unsigned short* wgb = wb + (size_t)N_ * K_;
  float* g = (float*)(wgb + (size_t)64 * K_);

  cvt3_kernel<<<(N4X + N4W + N4G + 255) / 256, 256, 0, stream>>>(x, We, Wg, bf, xb, wb, wgb, out);
  logits_softmax_kernel<<<B_ / 128, 256, 0, stream>>>(xb, wgb, bg, g);
  dim3 grid(B_ / 128, N_ / 128);  // x = mb, y = nb
  moe_main_kernel<<<grid, 256, 0, stream>>>(xb, wb, be, Wf, g, out);
}